// Round 1
// baseline (905.366 us; speedup 1.0000x reference)
//
#include <hip/hip_runtime.h>

#define NB 8
#define NN 4096
#define NS 1024
#define NK 64
#define NC 64
// MLP: in 67 -> 64 -> 128 -> 256
#define OUT_PTS_OFF (NB*NS*3)   // 24576

__global__ __launch_bounds__(256) void pointnet_sa(
    const float* __restrict__ xyz,      // (B,N,3)
    const float* __restrict__ points,   // (B,N,C)
    const int*   __restrict__ fps_inds, // (B,S)
    const float* __restrict__ w0,       // (67,64)
    const float* __restrict__ w1,       // (64,128)
    const float* __restrict__ w2,       // (128,256)
    float* __restrict__ out)            // new_xyz (B,S,3) ++ new_points (B,S,256)
{
  // LDS overlays:
  //  sm1: sdist[4096]u  ->  feat[64][68]  ->  h2[64][130]
  //  sm2: h1[64][66]    ->  redu[8][256]
  __shared__ float sm1[64*130];        // 33280 B
  __shared__ float sm2[64*66];         // 16896 B
  __shared__ unsigned int hist[256];   // also baseM
  __shared__ unsigned int scanbuf[256];
  __shared__ int sidx[NK];
  __shared__ unsigned int bc[4];

  const int q   = blockIdx.x;          // b*S + s
  const int b   = q >> 10;
  const int tid = threadIdx.x;

  const float* xb = xyz + (size_t)b * NN * 3;

  const int fps = fps_inds[q];
  const float qx = xb[fps*3+0], qy = xb[fps*3+1], qz = xb[fps*3+2];
  if (tid < 3) out[q*3 + tid] = xb[fps*3 + tid];

  // ---------------- phase 1: distances (bit-exact fp32, no FMA) ----------------
  unsigned int* sdist = (unsigned int*)sm1;
  for (int i = tid; i < NN; i += 256) {
    float dx = __fsub_rn(qx, xb[i*3+0]);
    float dy = __fsub_rn(qy, xb[i*3+1]);
    float dz = __fsub_rn(qz, xb[i*3+2]);
    float d2 = __fadd_rn(__fadd_rn(__fmul_rn(dx,dx), __fmul_rn(dy,dy)), __fmul_rn(dz,dz));
    sdist[i] = __float_as_uint(__fsqrt_rn(d2));
  }
  __syncthreads();

  // ---------------- radix select: 64th smallest distance T ----------------
  unsigned int prefix = 0u;
  int remaining = NK;                      // 1-indexed rank within candidates
  for (int shift = 24; shift >= 0; shift -= 8) {
    hist[tid] = 0u;
    __syncthreads();
    const unsigned int maskhi = (shift == 24) ? 0u : (0xFFFFFFFFu << (shift + 8));
    for (int i = tid; i < NN; i += 256) {
      unsigned int v = sdist[i];
      if ((v & maskhi) == prefix) atomicAdd(&hist[(v >> shift) & 255u], 1u);
    }
    __syncthreads();
    if (tid == 0) {
      unsigned int cum = 0, d = 0;
      for (; d < 256u; ++d) {
        unsigned int h = hist[d];
        if ((unsigned int)remaining <= cum + h) break;
        cum += h;
      }
      bc[0] = d; bc[1] = cum;
    }
    __syncthreads();
    prefix |= bc[0] << shift;
    remaining -= (int)bc[1];
  }
  const unsigned int T = prefix;           // 64th smallest dist bits
  const unsigned int Rbits = 0x3E4CCCCDu;  // bits of 0.2f

  // valid set: if T < R: all 64 selected (need `remaining` smallest-index ties at T)
  //            else: every dist < R (count <= 63), pad with min index
  unsigned int lim; int need_ties;
  if (T < Rbits) { lim = T;     need_ties = remaining; }
  else           { lim = Rbits; need_ties = 0;         }

  const int base_i = tid * 16;             // contiguous 16-element chunk per thread
  {
    unsigned int cL = 0, cT = 0;
    #pragma unroll
    for (int r = 0; r < 16; ++r) {
      unsigned int v = sdist[base_i + r];
      cL += (v < lim);
      cT += (v == T);
    }
    scanbuf[tid] = cL | (cT << 16);
  }
  __syncthreads();
  unsigned int* baseM = hist;              // reuse
  if (tid == 0) {
    unsigned int accT = 0, accM = 0;
    for (int t = 0; t < 256; ++t) {
      unsigned int pk = scanbuf[t];
      unsigned int l = pk & 0xFFFFu, tt = pk >> 16;
      int takeT = need_ties - (int)accT;
      if (takeT < 0) takeT = 0;
      if (takeT > (int)tt) takeT = (int)tt;
      baseM[t] = accM | (accT << 16);
      accM += l + (unsigned int)takeT;
      accT += tt;
    }
    bc[2] = accM;                          // total valid count mv (>=1 always)
  }
  __syncthreads();
  const int mv = (int)bc[2];
  {
    unsigned int pk = baseM[tid];
    int posM = (int)(pk & 0xFFFFu);
    int tieB = (int)(pk >> 16);
    #pragma unroll
    for (int r = 0; r < 16; ++r) {
      unsigned int v = sdist[base_i + r];
      bool memb = (v < lim);
      if (v == T) { if (!memb && tieB < need_ties) memb = true; tieB++; }
      if (memb) sidx[posM++] = base_i + r;
    }
  }
  __syncthreads();
  if (tid < NK && tid >= mv) sidx[tid] = sidx[0];  // pad with min valid index
  __syncthreads();

  // ---------------- phase 2: gather feat[64][67] ----------------
  float* feat = sm1;                       // overlays sdist (dead now), stride 68
  {
    const float* pb = points + (size_t)b * NN * NC;
    const int r = tid >> 2, part = tid & 3;
    const int nidx = sidx[r];
    const float4* prow = (const float4*)(pb + (size_t)nidx * NC + part * 16);
    float* frow = feat + r*68 + 3 + part*16;
    float4 v0 = prow[0], v1 = prow[1], v2 = prow[2], v3 = prow[3];
    frow[0]=v0.x;  frow[1]=v0.y;  frow[2]=v0.z;  frow[3]=v0.w;
    frow[4]=v1.x;  frow[5]=v1.y;  frow[6]=v1.z;  frow[7]=v1.w;
    frow[8]=v2.x;  frow[9]=v2.y;  frow[10]=v2.z; frow[11]=v2.w;
    frow[12]=v3.x; frow[13]=v3.y; frow[14]=v3.z; frow[15]=v3.w;
    if (part == 0) {
      float* f0 = feat + r*68;
      f0[0] = __fsub_rn(xb[nidx*3+0], qx);
      f0[1] = __fsub_rn(xb[nidx*3+1], qy);
      f0[2] = __fsub_rn(xb[nidx*3+2], qz);
    }
  }
  __syncthreads();

  // ---------------- layer 1: (64x67)@(67x64) -> h1, relu ----------------
  float* h1 = sm2;                         // stride 66
  {
    const int ty = tid >> 4, tx = tid & 15;
    float acc[4][4] = {};
    const float* f0 = feat + ty*4*68;
    for (int kk = 0; kk < 67; ++kk) {
      float a[4] = { f0[kk], f0[kk+68], f0[kk+136], f0[kk+204] };
      float4 wv = *(const float4*)(w0 + kk*64 + tx*4);
      float wj[4] = { wv.x, wv.y, wv.z, wv.w };
      #pragma unroll
      for (int i = 0; i < 4; ++i)
        #pragma unroll
        for (int j = 0; j < 4; ++j)
          acc[i][j] = fmaf(a[i], wj[j], acc[i][j]);
    }
    #pragma unroll
    for (int i = 0; i < 4; ++i)
      #pragma unroll
      for (int j = 0; j < 4; ++j)
        h1[(ty*4+i)*66 + tx*4 + j] = fmaxf(acc[i][j], 0.0f);
  }
  __syncthreads();

  // ---------------- layer 2: (64x64)@(64x128) -> h2, relu ----------------
  float* h2 = sm1;                         // overlays feat (dead), stride 130
  {
    const int ty = tid >> 4, tx = tid & 15;
    float acc[4][8] = {};
    const float* hr = h1 + ty*4*66;
    for (int kk = 0; kk < 64; ++kk) {
      float a[4] = { hr[kk], hr[kk+66], hr[kk+132], hr[kk+198] };
      float4 wa = *(const float4*)(w1 + kk*128 + tx*8);
      float4 wb = *(const float4*)(w1 + kk*128 + tx*8 + 4);
      float wj[8] = { wa.x, wa.y, wa.z, wa.w, wb.x, wb.y, wb.z, wb.w };
      #pragma unroll
      for (int i = 0; i < 4; ++i)
        #pragma unroll
        for (int j = 0; j < 8; ++j)
          acc[i][j] = fmaf(a[i], wj[j], acc[i][j]);
    }
    #pragma unroll
    for (int i = 0; i < 4; ++i)
      #pragma unroll
      for (int j = 0; j < 8; ++j)
        h2[(ty*4+i)*130 + tx*8 + j] = fmaxf(acc[i][j], 0.0f);
  }
  __syncthreads();

  // ---------------- layer 3: (64x128)@(128x256), relu, max over rows ----------------
  {
    const int ry = tid >> 5, fx = tid & 31;  // 8 rows x 8 cols per thread
    float acc[8][8] = {};
    const float* hr = h2 + ry*8*130;
    for (int kk = 0; kk < 128; ++kk) {
      float a[8];
      #pragma unroll
      for (int i = 0; i < 8; ++i) a[i] = hr[kk + i*130];
      float4 wa = *(const float4*)(w2 + kk*256 + fx*8);
      float4 wb = *(const float4*)(w2 + kk*256 + fx*8 + 4);
      float wj[8] = { wa.x, wa.y, wa.z, wa.w, wb.x, wb.y, wb.z, wb.w };
      #pragma unroll
      for (int i = 0; i < 8; ++i)
        #pragma unroll
        for (int j = 0; j < 8; ++j)
          acc[i][j] = fmaf(a[i], wj[j], acc[i][j]);
    }
    float* redu = sm2;                     // overlays h1 (dead): [8][256]
    #pragma unroll
    for (int j = 0; j < 8; ++j) {
      float m = acc[0][j];
      #pragma unroll
      for (int i = 1; i < 8; ++i) m = fmaxf(m, acc[i][j]);
      m = fmaxf(m, 0.0f);                  // relu(max) == max(relu)
      redu[ry*256 + fx*8 + j] = m;
    }
  }
  __syncthreads();
  {
    const float* redu = sm2;
    float m = redu[tid];
    #pragma unroll
    for (int r = 1; r < 8; ++r) m = fmaxf(m, redu[r*256 + tid]);
    out[OUT_PTS_OFF + q*256 + tid] = m;
  }
}

extern "C" void kernel_launch(void* const* d_in, const int* in_sizes, int n_in,
                              void* d_out, int out_size, void* d_ws, size_t ws_size,
                              hipStream_t stream) {
  const float* xyz      = (const float*)d_in[0];
  const float* points   = (const float*)d_in[1];
  const int*   fps_inds = (const int*)d_in[2];
  const float* w0       = (const float*)d_in[3];
  const float* w1       = (const float*)d_in[4];
  const float* w2       = (const float*)d_in[5];
  float* out = (float*)d_out;

  dim3 grid(NB * NS), block(256);
  hipLaunchKernelGGL(pointnet_sa, grid, block, 0, stream,
                     xyz, points, fps_inds, w0, w1, w2, out);
}

// Round 2
// 130.508 us; speedup vs baseline: 6.9372x; 6.9372x over previous
//
#include <hip/hip_runtime.h>

#define NB 8
#define NN 4096
#define NS 1024
#define NC 64
#define OUT_PTS_OFF (NB*NS*3)
#define CAP 512
#define RB 0.2f

typedef __attribute__((ext_vector_type(8))) short bf16x8;
typedef __attribute__((ext_vector_type(4))) float f32x4;

static __device__ __forceinline__ short f2bf(float f){
  unsigned u = __float_as_uint(f);
  unsigned r = (u + 0x7FFFu + ((u>>16)&1u)) >> 16;
  return (short)r;
}

// ws layout (shorts): wf0 [3][4][64][8] @0 ; wf1 [2][8][64][8] @6144 ; wf2 [4][16][64][8] @14336
// total 47104 shorts = 94208 B
__global__ __launch_bounds__(256) void prep_weights(
    const float* __restrict__ w0, const float* __restrict__ w1,
    const float* __restrict__ w2, short* __restrict__ ws)
{
  int e = blockIdx.x*256 + threadIdx.x;
  if (e >= 47104) return;
  float v = 0.f;
  if (e < 6144) {
    int j=e&7, l=(e>>3)&63, nt=(e>>9)&3, kt=e>>11;
    int k = kt*32 + ((l>>4)<<3) + j, n = nt*16 + (l&15);
    // permuted feature order: [points(64), dx,dy,dz, pad...]
    if (k < 64) v = w0[(3+k)*64 + n];
    else if (k < 67) v = w0[(k-64)*64 + n];
  } else if (e < 14336) {
    int e2=e-6144;
    int j=e2&7, l=(e2>>3)&63, nt=(e2>>9)&7, kt=e2>>12;
    int k = kt*32 + ((l>>4)<<3) + j, n = nt*16 + (l&15);
    v = w1[k*128 + n];
  } else {
    int e3=e-14336;
    int j=e3&7, l=(e3>>3)&63, nt=(e3>>9)&15, kt=e3>>13;
    int k = kt*32 + ((l>>4)<<3) + j, n = nt*16 + (l&15);
    v = w2[k*256 + n];
  }
  ws[e] = f2bf(v);
}

__global__ __launch_bounds__(256,4) void pointnet_sa(
    const float* __restrict__ xyz, const float* __restrict__ points,
    const int* __restrict__ fps_inds, const short* __restrict__ wsb,
    float* __restrict__ out)
{
  __shared__ unsigned int cand_d[CAP];
  __shared__ int cand_i[CAP];
  __shared__ int scnt[256];
  __shared__ int chunkbase[64];
  __shared__ int sidx[64];
  __shared__ int tmp64[64];
  __shared__ int sc0;
  __shared__ short h1[64][72];    // 16B-aligned rows (144B stride)
  __shared__ short h2[64][136];   // 272B stride

  const int q = blockIdx.x, b = q >> 10, tid = threadIdx.x;
  const float* xb = xyz + (size_t)b*NN*3;
  const int fps = fps_inds[q];
  const float qx = xb[fps*3+0], qy = xb[fps*3+1], qz = xb[fps*3+2];
  if (tid < 3) out[q*3+tid] = xb[fps*3+tid];

  // ---- pass A: exact distances for 16 contiguous points per thread ----
  unsigned int dbits[16]; unsigned int msk=0; int c=0;
  {
    const float4* xv = (const float4*)(xb + tid*48);
    #pragma unroll
    for (int g=0; g<4; ++g) {
      float4 v0 = xv[g*3], v1 = xv[g*3+1], v2 = xv[g*3+2];
      float px[4] = {v0.x, v0.w, v1.z, v2.y};
      float py[4] = {v0.y, v1.x, v1.w, v2.z};
      float pz[4] = {v0.z, v1.y, v2.x, v2.w};
      #pragma unroll
      for (int u=0; u<4; ++u) {
        float dx=__fsub_rn(qx,px[u]), dy=__fsub_rn(qy,py[u]), dz=__fsub_rn(qz,pz[u]);
        float d2=__fadd_rn(__fadd_rn(__fmul_rn(dx,dx),__fmul_rn(dy,dy)),__fmul_rn(dz,dz));
        float d = __fsqrt_rn(d2);
        dbits[g*4+u] = __float_as_uint(d);
        if (d < RB) { msk |= 1u<<(g*4+u); c++; }
      }
    }
  }

  // ---- exclusive scan of per-thread counts (order-preserving compaction) ----
  scnt[tid] = c; __syncthreads();
  if (tid < 64) {
    int s = scnt[tid*4]+scnt[tid*4+1]+scnt[tid*4+2]+scnt[tid*4+3];
    int incl = s;
    #pragma unroll
    for (int off=1; off<64; off<<=1) {
      int vv = __shfl_up(incl, off, 64);
      if (tid >= off) incl += vv;
    }
    chunkbase[tid] = incl - s;
    if (tid == 63) sc0 = incl;
  }
  __syncthreads();
  int cnt = sc0; if (cnt > CAP) cnt = CAP;
  {
    int base = chunkbase[tid>>2];
    for (int u = (tid & ~3); u < tid; ++u) base += scnt[u];
    #pragma unroll
    for (int r=0; r<16; ++r) {
      if (msk & (1u<<r)) {
        if (base < CAP) { cand_d[base] = dbits[r]; cand_i[base] = tid*16+r; }
        base++;
      }
    }
  }
  __syncthreads();

  // ---- select 64 smallest by (dist, idx); output in ascending index order ----
  if (cnt > 64) {
    for (int j=tid; j<cnt; j+=256) {
      unsigned dj = cand_d[j]; int rk=0;
      for (int i=0;i<cnt;++i) { unsigned di=cand_d[i]; rk += (int)((di<dj) | ((di==dj) & (i<j))); }
      if (rk < 64) tmp64[rk] = cand_i[j];
    }
    __syncthreads();
    if (tid < 64) {
      int v = tmp64[tid]; int p=0;
      for (int u=0;u<64;++u) p += (tmp64[u] < v);
      sidx[p] = v;
    }
  } else {
    if (tid < 64) sidx[tid] = cand_i[tid < cnt ? tid : 0];
  }
  __syncthreads();

  // ---- MFMA MLP: wave w owns rows 16w..16w+15 for layers 1-2 ----
  const int w = tid>>6, l = tid&63, lr = l&15, grp = l>>4;
  const float* pb = points + (size_t)b*NN*NC;
  const int myrow = w*16 + lr;
  const int idx = sidx[myrow];
  const float* prow = pb + (size_t)idx*NC;

  f32x4 zero4 = {0.f,0.f,0.f,0.f};

  // layer-1 A fragments straight from global (feature order: points[0..63], dxyz, pad)
  bf16x8 a0, a1, a2;
  {
    float4 u0 = *(const float4*)(prow + grp*8);
    float4 u1 = *(const float4*)(prow + grp*8 + 4);
    float4 u2 = *(const float4*)(prow + 32 + grp*8);
    float4 u3 = *(const float4*)(prow + 32 + grp*8 + 4);
    a0 = (bf16x8){f2bf(u0.x),f2bf(u0.y),f2bf(u0.z),f2bf(u0.w),f2bf(u1.x),f2bf(u1.y),f2bf(u1.z),f2bf(u1.w)};
    a1 = (bf16x8){f2bf(u2.x),f2bf(u2.y),f2bf(u2.z),f2bf(u2.w),f2bf(u3.x),f2bf(u3.y),f2bf(u3.z),f2bf(u3.w)};
    short e0=0,e1=0,e2v=0;
    if (grp==0) {
      e0 = f2bf(__fsub_rn(xb[idx*3+0], qx));
      e1 = f2bf(__fsub_rn(xb[idx*3+1], qy));
      e2v= f2bf(__fsub_rn(xb[idx*3+2], qz));
    }
    a2 = (bf16x8){e0,e1,e2v,0,0,0,0,0};
  }

  // ---- layer 1: 16x96 @ 96x64 ----
  #pragma unroll
  for (int nt=0; nt<4; ++nt) {
    f32x4 acc = zero4;
    bf16x8 b0 = *(const bf16x8*)(wsb + (((0*4+nt)*64 + l)<<3));
    bf16x8 b1 = *(const bf16x8*)(wsb + (((1*4+nt)*64 + l)<<3));
    bf16x8 b2 = *(const bf16x8*)(wsb + (((2*4+nt)*64 + l)<<3));
    acc = __builtin_amdgcn_mfma_f32_16x16x32_bf16(a0, b0, acc, 0,0,0);
    acc = __builtin_amdgcn_mfma_f32_16x16x32_bf16(a1, b1, acc, 0,0,0);
    acc = __builtin_amdgcn_mfma_f32_16x16x32_bf16(a2, b2, acc, 0,0,0);
    #pragma unroll
    for (int i=0;i<4;++i)
      h1[w*16 + grp*4 + i][nt*16 + lr] = f2bf(fmaxf(acc[i], 0.f));
  }

  // ---- layer 2: 16x64 @ 64x128 (wave-private, no barrier needed) ----
  bf16x8 a20 = *(const bf16x8*)&h1[myrow][grp*8];
  bf16x8 a21 = *(const bf16x8*)&h1[myrow][32 + grp*8];
  #pragma unroll
  for (int nt=0; nt<8; ++nt) {
    f32x4 acc = zero4;
    bf16x8 b0 = *(const bf16x8*)(wsb + 6144 + (((0*8+nt)*64 + l)<<3));
    bf16x8 b1 = *(const bf16x8*)(wsb + 6144 + (((1*8+nt)*64 + l)<<3));
    acc = __builtin_amdgcn_mfma_f32_16x16x32_bf16(a20, b0, acc, 0,0,0);
    acc = __builtin_amdgcn_mfma_f32_16x16x32_bf16(a21, b1, acc, 0,0,0);
    #pragma unroll
    for (int i=0;i<4;++i)
      h2[w*16 + grp*4 + i][nt*16 + lr] = f2bf(fmaxf(acc[i], 0.f));
  }
  __syncthreads();

  // ---- layer 3: wave w owns output ntiles 4w..4w+3, all 64 rows; fused maxpool ----
  #pragma unroll
  for (int pair=0; pair<2; ++pair) {
    f32x4 acc[4][2];
    #pragma unroll
    for (int mt=0; mt<4; ++mt) { acc[mt][0]=zero4; acc[mt][1]=zero4; }
    const int nt0 = w*4 + pair*2, nt1 = nt0+1;
    #pragma unroll
    for (int kt=0; kt<4; ++kt) {
      bf16x8 b0 = *(const bf16x8*)(wsb + 14336 + (((kt*16+nt0)*64 + l)<<3));
      bf16x8 b1 = *(const bf16x8*)(wsb + 14336 + (((kt*16+nt1)*64 + l)<<3));
      #pragma unroll
      for (int mt=0; mt<4; ++mt) {
        bf16x8 a = *(const bf16x8*)&h2[mt*16 + lr][kt*32 + grp*8];
        acc[mt][0] = __builtin_amdgcn_mfma_f32_16x16x32_bf16(a, b0, acc[mt][0], 0,0,0);
        acc[mt][1] = __builtin_amdgcn_mfma_f32_16x16x32_bf16(a, b1, acc[mt][1], 0,0,0);
      }
    }
    #pragma unroll
    for (int n2=0; n2<2; ++n2) {
      float m = 0.f;   // relu folded into maxpool
      #pragma unroll
      for (int mt=0; mt<4; ++mt)
        #pragma unroll
        for (int i=0; i<4; ++i) m = fmaxf(m, acc[mt][n2][i]);
      m = fmaxf(m, __shfl_xor(m, 16, 64));
      m = fmaxf(m, __shfl_xor(m, 32, 64));
      if (grp == 0) out[OUT_PTS_OFF + q*256 + (nt0+n2)*16 + lr] = m;
    }
  }
}

extern "C" void kernel_launch(void* const* d_in, const int* in_sizes, int n_in,
                              void* d_out, int out_size, void* d_ws, size_t ws_size,
                              hipStream_t stream) {
  const float* xyz      = (const float*)d_in[0];
  const float* points   = (const float*)d_in[1];
  const int*   fps_inds = (const int*)d_in[2];
  const float* w0       = (const float*)d_in[3];
  const float* w1       = (const float*)d_in[4];
  const float* w2       = (const float*)d_in[5];
  float* out = (float*)d_out;
  short* ws  = (short*)d_ws;

  hipLaunchKernelGGL(prep_weights, dim3(184), dim3(256), 0, stream, w0, w1, w2, ws);
  hipLaunchKernelGGL(pointnet_sa, dim3(NB*NS), dim3(256), 0, stream,
                     xyz, points, fps_inds, ws, out);
}

// Round 3
// 113.078 us; speedup vs baseline: 8.0065x; 1.1541x over previous
//
#include <hip/hip_runtime.h>

#define NB 8
#define NN 4096
#define NS 1024
#define NC 64
#define OUT_PTS_OFF (NB*NS*3)
#define CAP 512
#define RB 0.2f

typedef __attribute__((ext_vector_type(8))) short bf16x8;
typedef __attribute__((ext_vector_type(4))) float f32x4;

static __device__ __forceinline__ short f2bf(float f){
  unsigned u = __float_as_uint(f);
  unsigned r = (u + 0x7FFFu + ((u>>16)&1u)) >> 16;
  return (short)r;
}
static __device__ __forceinline__ float bf2f(short s){
  return __uint_as_float(((unsigned)(unsigned short)s) << 16);
}

// ws layout:
//   int   gsidx[8192][64]            @ byte 0        (2 MB)
//   short px1  [32768][64]           @ byte 2097152  (4 MB)
//   short wf   [47104]               @ byte 6291456  (94 KB)
//     wf0 [3][4][64][8] @0 ; wf1 [2][8][64][8] @6144 ; wf2 [4][16][64][8] @14336
#define WS_PX1_SH   1048576
#define WS_WF_SH    3145728

__global__ __launch_bounds__(256) void prep_weights(
    const float* __restrict__ w0, const float* __restrict__ w1,
    const float* __restrict__ w2, short* __restrict__ ws)
{
  int e = blockIdx.x*256 + threadIdx.x;
  if (e >= 47104) return;
  float v = 0.f;
  if (e < 6144) {
    int j=e&7, l=(e>>3)&63, nt=(e>>9)&3, kt=e>>11;
    int k = kt*32 + ((l>>4)<<3) + j, n = nt*16 + (l&15);
    // permuted feature order: [points(64), x,y,z, pad...]
    if (k < 64) v = w0[(3+k)*64 + n];
    else if (k < 67) v = w0[(k-64)*64 + n];
  } else if (e < 14336) {
    int e2=e-6144;
    int j=e2&7, l=(e2>>3)&63, nt=(e2>>9)&7, kt=e2>>12;
    int k = kt*32 + ((l>>4)<<3) + j, n = nt*16 + (l&15);
    v = w1[k*128 + n];
  } else {
    int e3=e-14336;
    int j=e3&7, l=(e3>>3)&63, nt=(e3>>9)&15, kt=e3>>13;
    int k = kt*32 + ((l>>4)<<3) + j, n = nt*16 + (l&15);
    v = w2[k*256 + n];
  }
  ws[e] = f2bf(v);
}

// ---- PX1[b,n,f] = ([points, xyz] @ w0_perm)[b,n,f]   (bf16, NO relu) ----
__global__ __launch_bounds__(256) void px1_kernel(
    const float* __restrict__ xyz, const float* __restrict__ points,
    const short* __restrict__ wsb, short* __restrict__ px1)
{
  const int tid = threadIdx.x;
  const int w = tid>>6, l = tid&63, lr = l&15, grp = l>>4;
  const int rowbase = blockIdx.x*64 + w*16;
  const int row = rowbase + lr;                 // global point row in [0, 32768)
  const float* prow = points + (size_t)row*NC;
  const float* xr   = xyz + (size_t)row*3;

  bf16x8 a0, a1, a2;
  {
    float4 u0 = *(const float4*)(prow + grp*8);
    float4 u1 = *(const float4*)(prow + grp*8 + 4);
    float4 u2 = *(const float4*)(prow + 32 + grp*8);
    float4 u3 = *(const float4*)(prow + 32 + grp*8 + 4);
    a0 = (bf16x8){f2bf(u0.x),f2bf(u0.y),f2bf(u0.z),f2bf(u0.w),f2bf(u1.x),f2bf(u1.y),f2bf(u1.z),f2bf(u1.w)};
    a1 = (bf16x8){f2bf(u2.x),f2bf(u2.y),f2bf(u2.z),f2bf(u2.w),f2bf(u3.x),f2bf(u3.y),f2bf(u3.z),f2bf(u3.w)};
    short e0=0,e1=0,e2v=0;
    if (grp==0) { e0=f2bf(xr[0]); e1=f2bf(xr[1]); e2v=f2bf(xr[2]); }
    a2 = (bf16x8){e0,e1,e2v,0,0,0,0,0};
  }
  f32x4 zero4 = {0.f,0.f,0.f,0.f};
  #pragma unroll
  for (int nt=0; nt<4; ++nt) {
    f32x4 acc = zero4;
    bf16x8 b0 = *(const bf16x8*)(wsb + (((0*4+nt)*64 + l)<<3));
    bf16x8 b1 = *(const bf16x8*)(wsb + (((1*4+nt)*64 + l)<<3));
    bf16x8 b2 = *(const bf16x8*)(wsb + (((2*4+nt)*64 + l)<<3));
    acc = __builtin_amdgcn_mfma_f32_16x16x32_bf16(a0, b0, acc, 0,0,0);
    acc = __builtin_amdgcn_mfma_f32_16x16x32_bf16(a1, b1, acc, 0,0,0);
    acc = __builtin_amdgcn_mfma_f32_16x16x32_bf16(a2, b2, acc, 0,0,0);
    #pragma unroll
    for (int i=0;i<4;++i)
      px1[(size_t)(rowbase + grp*4 + i)*64 + nt*16 + lr] = f2bf(acc[i]);
  }
}

// ---- selection: exact query_ball_point semantics, writes gsidx + new_xyz ----
__global__ __launch_bounds__(256) void select_kernel(
    const float* __restrict__ xyz, const int* __restrict__ fps_inds,
    int* __restrict__ gsidx, float* __restrict__ out)
{
  __shared__ unsigned int cand_d[CAP];
  __shared__ int cand_i[CAP];
  __shared__ int scnt[256];
  __shared__ int chunkbase[64];
  __shared__ int tmp64[64];
  __shared__ int sc0;

  const int q = blockIdx.x, b = q >> 10, tid = threadIdx.x;
  const float* xb = xyz + (size_t)b*NN*3;
  const int fps = fps_inds[q];
  const float qx = xb[fps*3+0], qy = xb[fps*3+1], qz = xb[fps*3+2];
  if (tid < 3) out[q*3+tid] = xb[fps*3+tid];

  unsigned int dbits[16]; unsigned int msk=0; int c=0;
  {
    const float4* xv = (const float4*)(xb + tid*48);
    #pragma unroll
    for (int g=0; g<4; ++g) {
      float4 v0 = xv[g*3], v1 = xv[g*3+1], v2 = xv[g*3+2];
      float px[4] = {v0.x, v0.w, v1.z, v2.y};
      float py[4] = {v0.y, v1.x, v1.w, v2.z};
      float pz[4] = {v0.z, v1.y, v2.x, v2.w};
      #pragma unroll
      for (int u=0; u<4; ++u) {
        float dx=__fsub_rn(qx,px[u]), dy=__fsub_rn(qy,py[u]), dz=__fsub_rn(qz,pz[u]);
        float d2=__fadd_rn(__fadd_rn(__fmul_rn(dx,dx),__fmul_rn(dy,dy)),__fmul_rn(dz,dz));
        float d = __fsqrt_rn(d2);
        dbits[g*4+u] = __float_as_uint(d);
        if (d < RB) { msk |= 1u<<(g*4+u); c++; }
      }
    }
  }
  scnt[tid] = c; __syncthreads();
  if (tid < 64) {
    int s = scnt[tid*4]+scnt[tid*4+1]+scnt[tid*4+2]+scnt[tid*4+3];
    int incl = s;
    #pragma unroll
    for (int off=1; off<64; off<<=1) {
      int vv = __shfl_up(incl, off, 64);
      if (tid >= off) incl += vv;
    }
    chunkbase[tid] = incl - s;
    if (tid == 63) sc0 = incl;
  }
  __syncthreads();
  int cnt = sc0; if (cnt > CAP) cnt = CAP;
  {
    int base = chunkbase[tid>>2];
    for (int u = (tid & ~3); u < tid; ++u) base += scnt[u];
    #pragma unroll
    for (int r=0; r<16; ++r) {
      if (msk & (1u<<r)) {
        if (base < CAP) { cand_d[base] = dbits[r]; cand_i[base] = tid*16+r; }
        base++;
      }
    }
  }
  __syncthreads();

  if (cnt > 64) {
    for (int j=tid; j<cnt; j+=256) {
      unsigned dj = cand_d[j]; int rk=0;
      for (int i=0;i<cnt;++i) { unsigned di=cand_d[i]; rk += (int)((di<dj) | ((di==dj) & (i<j))); }
      if (rk < 64) tmp64[rk] = cand_i[j];
    }
    __syncthreads();
    if (tid < 64) {
      int v = tmp64[tid]; int p=0;
      for (int u=0;u<64;++u) p += (tmp64[u] < v);
      gsidx[q*64 + p] = v;
    }
  } else {
    if (tid < 64) gsidx[q*64 + tid] = cand_i[tid < cnt ? tid : 0];
  }
}

// ---- MLP: h1 = relu(PX1[idx]-Q1) gathered into A-frags; layers 2,3 + maxpool ----
__global__ __launch_bounds__(256,4) void mlp_kernel(
    const float* __restrict__ xyz, const int* __restrict__ fps_inds,
    const float* __restrict__ w0, const short* __restrict__ wsb,
    const short* __restrict__ px1, const int* __restrict__ gsidx,
    float* __restrict__ out)
{
  __shared__ short h2[64][136];
  __shared__ float q1s[64];
  __shared__ int sidx[64];

  const int q = blockIdx.x, b = q >> 10, tid = threadIdx.x;
  const float* xb = xyz + (size_t)b*NN*3;
  const int fps = fps_inds[q];
  const float qx = xb[fps*3+0], qy = xb[fps*3+1], qz = xb[fps*3+2];
  if (tid < 64) {
    sidx[tid] = gsidx[q*64 + tid];
    q1s[tid] = qx*w0[tid] + qy*w0[64+tid] + qz*w0[128+tid];
  }
  __syncthreads();

  const int w = tid>>6, l = tid&63, lr = l&15, grp = l>>4;
  const int myrow = w*16 + lr;
  const int idx = sidx[myrow];
  const short* pr = px1 + (size_t)(b*NN + idx)*64;

  f32x4 zero4 = {0.f,0.f,0.f,0.f};

  bf16x8 a20, a21;
  {
    bf16x8 v0 = *(const bf16x8*)(pr + grp*8);
    bf16x8 v1 = *(const bf16x8*)(pr + 32 + grp*8);
    #pragma unroll
    for (int j=0;j<8;++j) {
      a20[j] = f2bf(fmaxf(bf2f(v0[j]) - q1s[grp*8+j], 0.f));
      a21[j] = f2bf(fmaxf(bf2f(v1[j]) - q1s[32+grp*8+j], 0.f));
    }
  }

  // layer 2: 16x64 @ 64x128, wave-private
  #pragma unroll
  for (int nt=0; nt<8; ++nt) {
    f32x4 acc = zero4;
    bf16x8 b0 = *(const bf16x8*)(wsb + 6144 + (((0*8+nt)*64 + l)<<3));
    bf16x8 b1 = *(const bf16x8*)(wsb + 6144 + (((1*8+nt)*64 + l)<<3));
    acc = __builtin_amdgcn_mfma_f32_16x16x32_bf16(a20, b0, acc, 0,0,0);
    acc = __builtin_amdgcn_mfma_f32_16x16x32_bf16(a21, b1, acc, 0,0,0);
    #pragma unroll
    for (int i=0;i<4;++i)
      h2[w*16 + grp*4 + i][nt*16 + lr] = f2bf(fmaxf(acc[i], 0.f));
  }
  __syncthreads();

  // layer 3: wave w owns output ntiles 4w..4w+3, fused maxpool
  #pragma unroll
  for (int pair=0; pair<2; ++pair) {
    f32x4 acc[4][2];
    #pragma unroll
    for (int mt=0; mt<4; ++mt) { acc[mt][0]=zero4; acc[mt][1]=zero4; }
    const int nt0 = w*4 + pair*2, nt1 = nt0+1;
    #pragma unroll
    for (int kt=0; kt<4; ++kt) {
      bf16x8 b0 = *(const bf16x8*)(wsb + 14336 + (((kt*16+nt0)*64 + l)<<3));
      bf16x8 b1 = *(const bf16x8*)(wsb + 14336 + (((kt*16+nt1)*64 + l)<<3));
      #pragma unroll
      for (int mt=0; mt<4; ++mt) {
        bf16x8 a = *(const bf16x8*)&h2[mt*16 + lr][kt*32 + grp*8];
        acc[mt][0] = __builtin_amdgcn_mfma_f32_16x16x32_bf16(a, b0, acc[mt][0], 0,0,0);
        acc[mt][1] = __builtin_amdgcn_mfma_f32_16x16x32_bf16(a, b1, acc[mt][1], 0,0,0);
      }
    }
    #pragma unroll
    for (int n2=0; n2<2; ++n2) {
      float m = 0.f;
      #pragma unroll
      for (int mt=0; mt<4; ++mt)
        #pragma unroll
        for (int i=0; i<4; ++i) m = fmaxf(m, acc[mt][n2][i]);
      m = fmaxf(m, __shfl_xor(m, 16, 64));
      m = fmaxf(m, __shfl_xor(m, 32, 64));
      if (grp == 0) out[OUT_PTS_OFF + q*256 + (nt0+n2)*16 + lr] = m;
    }
  }
}

extern "C" void kernel_launch(void* const* d_in, const int* in_sizes, int n_in,
                              void* d_out, int out_size, void* d_ws, size_t ws_size,
                              hipStream_t stream) {
  const float* xyz      = (const float*)d_in[0];
  const float* points   = (const float*)d_in[1];
  const int*   fps_inds = (const int*)d_in[2];
  const float* w0       = (const float*)d_in[3];
  const float* w1       = (const float*)d_in[4];
  const float* w2       = (const float*)d_in[5];
  float* out = (float*)d_out;

  int*   gsidx = (int*)d_ws;
  short* px1   = (short*)d_ws + WS_PX1_SH;
  short* wsb   = (short*)d_ws + WS_WF_SH;

  hipLaunchKernelGGL(prep_weights, dim3(184), dim3(256), 0, stream, w0, w1, w2, wsb);
  hipLaunchKernelGGL(px1_kernel,   dim3(512), dim3(256), 0, stream, xyz, points, wsb, px1);
  hipLaunchKernelGGL(select_kernel,dim3(NB*NS), dim3(256), 0, stream, xyz, fps_inds, gsidx, out);
  hipLaunchKernelGGL(mlp_kernel,   dim3(NB*NS), dim3(256), 0, stream,
                     xyz, fps_inds, w0, wsb, px1, gsidx, out);
}